// Round 1
// baseline (1127.522 us; speedup 1.0000x reference)
//
#include <hip/hip_runtime.h>

#define RANK 128
#define LN_EPS 1e-5f

// ---------------- degree kernels ----------------
__global__ void deg_kernel(const int* __restrict__ src, const int* __restrict__ dst,
                           float* __restrict__ degout, float* __restrict__ degin, int nE) {
    int e = blockIdx.x * blockDim.x + threadIdx.x;
    if (e < nE) {
        atomicAdd(&degout[src[e]], 1.0f);
        atomicAdd(&degin[dst[e]], 1.0f);
    }
}

__global__ void inv_kernel(float* __restrict__ a, float* __restrict__ b, int n) {
    int i = blockIdx.x * blockDim.x + threadIdx.x;
    if (i < n) {
        a[i] = rsqrtf(fmaxf(a[i], 1.0f));
        b[i] = rsqrtf(fmaxf(b[i], 1.0f));
    }
}

// ---------------- fp32 GEMM: H = (X @ W) * invout[row] ----------------
// X: [M,128] row-major, W: [128,128] row-major, tile 64 rows x 128 cols
#define TM 64
#define KB 32
__global__ __launch_bounds__(256) void gemm_kernel(const float* __restrict__ X,
                                                   const float* __restrict__ W,
                                                   const float* __restrict__ invout,
                                                   float* __restrict__ H, int M) {
    __shared__ float Xs[TM][KB + 1];    // +1 pad
    __shared__ float Wls[KB][RANK];     // 16 KB

    int tid = threadIdx.x;
    int trow = tid >> 5;   // 0..7  -> 8 rows each
    int tcol = tid & 31;   // 0..31 -> 4 cols each
    int row0 = blockIdx.x * TM;

    float acc[8][4];
#pragma unroll
    for (int i = 0; i < 8; i++)
#pragma unroll
        for (int j = 0; j < 4; j++) acc[i][j] = 0.f;

    for (int k0 = 0; k0 < RANK; k0 += KB) {
        __syncthreads();
        // stage X: 64 rows x 32 k-floats; each thread: 2 float4 loads
        {
            int r = tid >> 3;            // 0..31
            int kk = (tid & 7) * 4;      // 0..28
#pragma unroll
            for (int it = 0; it < 2; it++) {
                int rr = r + it * 32;
                int grow = row0 + rr;
                float4 v = make_float4(0.f, 0.f, 0.f, 0.f);
                if (grow < M) v = *(const float4*)(X + (size_t)grow * RANK + k0 + kk);
                Xs[rr][kk + 0] = v.x; Xs[rr][kk + 1] = v.y;
                Xs[rr][kk + 2] = v.z; Xs[rr][kk + 3] = v.w;
            }
        }
        // stage W chunk: 32 rows x 128 = 4096 floats (contiguous)
        {
            const float4* Wg = (const float4*)(W + (size_t)k0 * RANK);
            float4* Wl = (float4*)&Wls[0][0];
#pragma unroll
            for (int i = 0; i < 4; i++) Wl[tid + i * 256] = Wg[tid + i * 256];
        }
        __syncthreads();
#pragma unroll
        for (int k = 0; k < KB; k++) {
            float4 w = *(const float4*)&Wls[k][tcol * 4];
#pragma unroll
            for (int i = 0; i < 8; i++) {
                float x = Xs[trow * 8 + i][k];
                acc[i][0] += x * w.x; acc[i][1] += x * w.y;
                acc[i][2] += x * w.z; acc[i][3] += x * w.w;
            }
        }
    }
#pragma unroll
    for (int i = 0; i < 8; i++) {
        int row = row0 + trow * 8 + i;
        if (row < M) {
            float s = invout[row];
            float4 o = make_float4(acc[i][0] * s, acc[i][1] * s, acc[i][2] * s, acc[i][3] * s);
            *(float4*)(H + (size_t)row * RANK + tcol * 4) = o;
        }
    }
}

// ---------------- edge scatter: agg[dst] += h[src] ----------------
__global__ __launch_bounds__(256) void scatter_kernel(const float* __restrict__ H,
                                                      const int* __restrict__ src,
                                                      const int* __restrict__ dst,
                                                      float* __restrict__ agg, int nE) {
    long long gid = (long long)blockIdx.x * blockDim.x + threadIdx.x;
    int e = (int)(gid >> 7);
    int c = (int)(gid & 127);
    if (e < nE) {
        int s = src[e];
        int d = dst[e];
        atomicAdd(&agg[(size_t)d * RANK + c], H[(size_t)s * RANK + c]);
    }
}

// ---------------- fused scale + bias + LayerNorm + ReLU ----------------
__global__ __launch_bounds__(256) void ln_kernel(const float* __restrict__ agg,
                                                 const float* __restrict__ invin,
                                                 const float* __restrict__ bias,
                                                 const float* __restrict__ gamma,
                                                 const float* __restrict__ beta,
                                                 float* __restrict__ out, int M) {
    int wid = threadIdx.x >> 6;
    int lane = threadIdx.x & 63;
    int node = blockIdx.x * 4 + wid;
    if (node >= M) return;

    float2 v = ((const float2*)(agg + (size_t)node * RANK))[lane];
    float s = invin[node];
    float2 b = ((const float2*)bias)[lane];
    float x0 = v.x * s + b.x;
    float x1 = v.y * s + b.y;

    float sum = x0 + x1;
    float sq = x0 * x0 + x1 * x1;
#pragma unroll
    for (int off = 32; off > 0; off >>= 1) {
        sum += __shfl_down(sum, off);
        sq  += __shfl_down(sq, off);
    }
    sum = __shfl(sum, 0);
    sq  = __shfl(sq, 0);
    float mu = sum * (1.0f / RANK);
    float var = sq * (1.0f / RANK) - mu * mu;
    float r = rsqrtf(var + LN_EPS);

    float2 g = ((const float2*)gamma)[lane];
    float2 be = ((const float2*)beta)[lane];
    float y0 = fmaxf((x0 - mu) * r * g.x + be.x, 0.f);
    float y1 = fmaxf((x1 - mu) * r * g.y + be.y, 0.f);
    ((float2*)(out + (size_t)node * RANK))[lane] = make_float2(y0, y1);
}

// ---------------- final gather of first node per graph ----------------
__global__ void gather_kernel(const float* __restrict__ feats, const int* __restrict__ bnn,
                              float* __restrict__ out, int nG) {
    int g = blockIdx.x;
    int c = threadIdx.x;
    int idx = 0;
    for (int i = 0; i < g; i++) idx += bnn[i];
    out[(size_t)g * RANK + c] = feats[(size_t)idx * RANK + c];
}

extern "C" void kernel_launch(void* const* d_in, const int* in_sizes, int n_in,
                              void* d_out, int out_size, void* d_ws, size_t ws_size,
                              hipStream_t stream) {
    const float* features = (const float*)d_in[0];
    const int* src = (const int*)d_in[1];
    const int* dst = (const int*)d_in[2];
    const int* bnn = (const int*)d_in[3];
    const float* Ws = (const float*)d_in[4];
    const float* bs = (const float*)d_in[5];
    const float* gammas = (const float*)d_in[6];
    const float* betas = (const float*)d_in[7];
    float* out = (float*)d_out;

    int M  = in_sizes[0] / RANK;   // 50000
    int nE = in_sizes[1];          // 640000
    int nG = in_sizes[3];          // 50

    // workspace layout
    char* ws = (char*)d_ws;
    size_t off = 0;
    auto alloc = [&](size_t bytes) {
        void* p = ws + off;
        off += (bytes + 255) & ~(size_t)255;
        return p;
    };
    float* invout = (float*)alloc((size_t)M * 4);
    float* invin  = (float*)alloc((size_t)M * 4);
    float* A      = (float*)alloc((size_t)M * RANK * 4);
    float* B      = (float*)alloc((size_t)M * RANK * 4);

    // degrees -> inverse sqrt
    hipMemsetAsync(invout, 0, (size_t)M * 4, stream);
    hipMemsetAsync(invin, 0, (size_t)M * 4, stream);
    deg_kernel<<<(nE + 255) / 256, 256, 0, stream>>>(src, dst, invout, invin, nE);
    inv_kernel<<<(M + 255) / 256, 256, 0, stream>>>(invout, invin, M);

    const float* fin = features;
    float* Xb = A;  // h buffer this layer; LN output lands here too
    float* Yb = B;  // agg buffer this layer
    long long scatter_items = (long long)nE * RANK;
    int scatter_blocks = (int)((scatter_items + 255) / 256);

    for (int l = 0; l < 3; l++) {
        gemm_kernel<<<(M + TM - 1) / TM, 256, 0, stream>>>(
            fin, Ws + (size_t)l * RANK * RANK, invout, Xb, M);
        hipMemsetAsync(Yb, 0, (size_t)M * RANK * 4, stream);
        scatter_kernel<<<scatter_blocks, 256, 0, stream>>>(Xb, src, dst, Yb, nE);
        ln_kernel<<<(M + 3) / 4, 256, 0, stream>>>(
            Yb, invin, bs + (size_t)l * RANK, gammas + (size_t)l * RANK,
            betas + (size_t)l * RANK, Xb, M);
        fin = Xb;
        float* t = Xb; Xb = Yb; Yb = t;
    }

    // fin points at the final features buffer
    gather_kernel<<<nG, RANK, 0, stream>>>(fin, bnn, out, nG);
}

// Round 2
// 413.177 us; speedup vs baseline: 2.7289x; 2.7289x over previous
//
#include <hip/hip_runtime.h>

#define RANK 128
#define LN_EPS 1e-5f

// ---------------- histogram: in-degree (counts) + out-degree ----------------
__global__ void hist_kernel(const int* __restrict__ src, const int* __restrict__ dst,
                            int* __restrict__ counts, int* __restrict__ outdeg, int nE) {
    int e = blockIdx.x * blockDim.x + threadIdx.x;
    if (e < nE) {
        atomicAdd(&counts[dst[e]], 1);
        atomicAdd(&outdeg[src[e]], 1);
    }
}

__global__ void inv_kernel(const int* __restrict__ outdeg, const int* __restrict__ counts,
                           float* __restrict__ invout, float* __restrict__ invin, int n) {
    int i = blockIdx.x * blockDim.x + threadIdx.x;
    if (i < n) {
        invout[i] = rsqrtf(fmaxf((float)outdeg[i], 1.0f));
        invin[i]  = rsqrtf(fmaxf((float)counts[i], 1.0f));
    }
}

// ---------------- prefix scan (3-phase, 256/block Hillis-Steele) ----------------
__global__ __launch_bounds__(256) void scan1_kernel(const int* __restrict__ counts,
                                                    int* __restrict__ cursor,
                                                    int* __restrict__ bsums, int n) {
    __shared__ int tmp[256];
    int tid = threadIdx.x;
    int gid = blockIdx.x * 256 + tid;
    int v = (gid < n) ? counts[gid] : 0;
    tmp[tid] = v;
    __syncthreads();
    for (int off = 1; off < 256; off <<= 1) {
        int t = (tid >= off) ? tmp[tid - off] : 0;
        __syncthreads();
        tmp[tid] += t;
        __syncthreads();
    }
    if (gid < n) cursor[gid] = tmp[tid];          // inclusive in-block
    if (tid == 255) bsums[blockIdx.x] = tmp[255]; // block total
}

__global__ __launch_bounds__(256) void scan2_kernel(int* __restrict__ bsums, int nb) {
    __shared__ int tmp[256];
    int tid = threadIdx.x;
    int v = (tid < nb) ? bsums[tid] : 0;
    tmp[tid] = v;
    __syncthreads();
    for (int off = 1; off < 256; off <<= 1) {
        int t = (tid >= off) ? tmp[tid - off] : 0;
        __syncthreads();
        tmp[tid] += t;
        __syncthreads();
    }
    if (tid < nb) bsums[tid] = tmp[tid] - v;      // exclusive
}

__global__ __launch_bounds__(256) void scan3_kernel(const int* __restrict__ counts,
                                                    int* __restrict__ cursor,
                                                    const int* __restrict__ bsums, int n) {
    int gid = blockIdx.x * 256 + threadIdx.x;
    if (gid < n) cursor[gid] += bsums[blockIdx.x] - counts[gid];  // exclusive start
}

// ---------------- CSR fill (cursor becomes inclusive-end after this) --------
__global__ void fill_kernel(const int* __restrict__ src, const int* __restrict__ dst,
                            int* __restrict__ cursor, int* __restrict__ csr_src, int nE) {
    int e = blockIdx.x * blockDim.x + threadIdx.x;
    if (e < nE) {
        int pos = atomicAdd(&cursor[dst[e]], 1);
        csr_src[pos] = src[e];
    }
}

// ---------------- fp32 GEMM: H = (X @ W) * invout[row] ----------------
#define TM 64
#define KB 32
__global__ __launch_bounds__(256) void gemm_kernel(const float* __restrict__ X,
                                                   const float* __restrict__ W,
                                                   const float* __restrict__ invout,
                                                   float* __restrict__ H, int M) {
    __shared__ float Xs[TM][KB + 1];
    __shared__ float Wls[KB][RANK];

    int tid = threadIdx.x;
    int trow = tid >> 5;
    int tcol = tid & 31;
    int row0 = blockIdx.x * TM;

    float acc[8][4];
#pragma unroll
    for (int i = 0; i < 8; i++)
#pragma unroll
        for (int j = 0; j < 4; j++) acc[i][j] = 0.f;

    for (int k0 = 0; k0 < RANK; k0 += KB) {
        __syncthreads();
        {
            int r = tid >> 3;
            int kk = (tid & 7) * 4;
#pragma unroll
            for (int it = 0; it < 2; it++) {
                int rr = r + it * 32;
                int grow = row0 + rr;
                float4 v = make_float4(0.f, 0.f, 0.f, 0.f);
                if (grow < M) v = *(const float4*)(X + (size_t)grow * RANK + k0 + kk);
                Xs[rr][kk + 0] = v.x; Xs[rr][kk + 1] = v.y;
                Xs[rr][kk + 2] = v.z; Xs[rr][kk + 3] = v.w;
            }
        }
        {
            const float4* Wg = (const float4*)(W + (size_t)k0 * RANK);
            float4* Wl = (float4*)&Wls[0][0];
#pragma unroll
            for (int i = 0; i < 4; i++) Wl[tid + i * 256] = Wg[tid + i * 256];
        }
        __syncthreads();
#pragma unroll
        for (int k = 0; k < KB; k++) {
            float4 w = *(const float4*)&Wls[k][tcol * 4];
#pragma unroll
            for (int i = 0; i < 8; i++) {
                float x = Xs[trow * 8 + i][k];
                acc[i][0] += x * w.x; acc[i][1] += x * w.y;
                acc[i][2] += x * w.z; acc[i][3] += x * w.w;
            }
        }
    }
#pragma unroll
    for (int i = 0; i < 8; i++) {
        int row = row0 + trow * 8 + i;
        if (row < M) {
            float s = invout[row];
            float4 o = make_float4(acc[i][0] * s, acc[i][1] * s, acc[i][2] * s, acc[i][3] * s);
            *(float4*)(H + (size_t)row * RANK + tcol * 4) = o;
        }
    }
}

// ---------------- fused CSR gather + scale + bias + LN + ReLU ----------------
// one wave (64 lanes) per dst node; float2 per lane = one 128-col row
__global__ __launch_bounds__(256) void gatherln_kernel(const float* __restrict__ H,
                                                       const int* __restrict__ cursor,  // inclusive ends
                                                       const int* __restrict__ csr_src,
                                                       const float* __restrict__ invin,
                                                       const float* __restrict__ bias,
                                                       const float* __restrict__ gamma,
                                                       const float* __restrict__ beta,
                                                       float* __restrict__ out, int M) {
    int wid = threadIdx.x >> 6;
    int lane = threadIdx.x & 63;
    int node = blockIdx.x * 4 + wid;
    if (node >= M) return;

    int end = cursor[node];
    int beg = (node == 0) ? 0 : cursor[node - 1];

    float ax = 0.f, ay = 0.f;
    int e = beg;
    for (; e + 4 <= end; e += 4) {
        int s0 = csr_src[e + 0], s1 = csr_src[e + 1];
        int s2 = csr_src[e + 2], s3 = csr_src[e + 3];
        float2 v0 = ((const float2*)(H + (size_t)s0 * RANK))[lane];
        float2 v1 = ((const float2*)(H + (size_t)s1 * RANK))[lane];
        float2 v2 = ((const float2*)(H + (size_t)s2 * RANK))[lane];
        float2 v3 = ((const float2*)(H + (size_t)s3 * RANK))[lane];
        ax += (v0.x + v1.x) + (v2.x + v3.x);
        ay += (v0.y + v1.y) + (v2.y + v3.y);
    }
    for (; e < end; e++) {
        int s = csr_src[e];
        float2 v = ((const float2*)(H + (size_t)s * RANK))[lane];
        ax += v.x;
        ay += v.y;
    }

    float s = invin[node];
    float2 b = ((const float2*)bias)[lane];
    float x0 = ax * s + b.x;
    float x1 = ay * s + b.y;

    float sum = x0 + x1;
    float sq = x0 * x0 + x1 * x1;
#pragma unroll
    for (int off = 32; off > 0; off >>= 1) {
        sum += __shfl_down(sum, off);
        sq  += __shfl_down(sq, off);
    }
    sum = __shfl(sum, 0);
    sq  = __shfl(sq, 0);
    float mu = sum * (1.0f / RANK);
    float var = sq * (1.0f / RANK) - mu * mu;
    float r = rsqrtf(var + LN_EPS);

    float2 g = ((const float2*)gamma)[lane];
    float2 be = ((const float2*)beta)[lane];
    float y0 = fmaxf((x0 - mu) * r * g.x + be.x, 0.f);
    float y1 = fmaxf((x1 - mu) * r * g.y + be.y, 0.f);
    ((float2*)(out + (size_t)node * RANK))[lane] = make_float2(y0, y1);
}

// ---------------- final gather of first node per graph ----------------
__global__ void gather_kernel(const float* __restrict__ feats, const int* __restrict__ bnn,
                              float* __restrict__ out, int nG) {
    int g = blockIdx.x;
    int c = threadIdx.x;
    int idx = 0;
    for (int i = 0; i < g; i++) idx += bnn[i];
    out[(size_t)g * RANK + c] = feats[(size_t)idx * RANK + c];
}

extern "C" void kernel_launch(void* const* d_in, const int* in_sizes, int n_in,
                              void* d_out, int out_size, void* d_ws, size_t ws_size,
                              hipStream_t stream) {
    const float* features = (const float*)d_in[0];
    const int* src = (const int*)d_in[1];
    const int* dst = (const int*)d_in[2];
    const int* bnn = (const int*)d_in[3];
    const float* Ws = (const float*)d_in[4];
    const float* bs = (const float*)d_in[5];
    const float* gammas = (const float*)d_in[6];
    const float* betas = (const float*)d_in[7];
    float* out = (float*)d_out;

    int M  = in_sizes[0] / RANK;   // 50000
    int nE = in_sizes[1];          // 640000
    int nG = in_sizes[3];          // 50

    // workspace layout
    char* ws = (char*)d_ws;
    size_t off = 0;
    auto alloc = [&](size_t bytes) {
        void* p = ws + off;
        off += (bytes + 255) & ~(size_t)255;
        return p;
    };
    int*   counts  = (int*)alloc((size_t)M * 4);
    int*   outdeg  = (int*)alloc((size_t)M * 4);
    int*   cursor  = (int*)alloc((size_t)M * 4);
    int*   bsums   = (int*)alloc(256 * 4);
    float* invout  = (float*)alloc((size_t)M * 4);
    float* invin   = (float*)alloc((size_t)M * 4);
    int*   csr_src = (int*)alloc((size_t)nE * 4);
    float* A       = (float*)alloc((size_t)M * RANK * 4);   // H (gemm out)
    float* B       = (float*)alloc((size_t)M * RANK * 4);   // layer out

    int nb = (M + 255) / 256;   // 196 <= 256

    // ---- CSR build + degree normalizers ----
    hipMemsetAsync(counts, 0, (size_t)M * 4, stream);
    hipMemsetAsync(outdeg, 0, (size_t)M * 4, stream);
    hist_kernel<<<(nE + 255) / 256, 256, 0, stream>>>(src, dst, counts, outdeg, nE);
    inv_kernel<<<(M + 255) / 256, 256, 0, stream>>>(outdeg, counts, invout, invin, M);
    scan1_kernel<<<nb, 256, 0, stream>>>(counts, cursor, bsums, M);
    scan2_kernel<<<1, 256, 0, stream>>>(bsums, nb);
    scan3_kernel<<<nb, 256, 0, stream>>>(counts, cursor, bsums, M);
    fill_kernel<<<(nE + 255) / 256, 256, 0, stream>>>(src, dst, cursor, csr_src, nE);
    // cursor[i] is now the inclusive end of node i's edge range

    // ---- 3 layers ----
    const float* fin = features;
    for (int l = 0; l < 3; l++) {
        gemm_kernel<<<(M + TM - 1) / TM, 256, 0, stream>>>(
            fin, Ws + (size_t)l * RANK * RANK, invout, A, M);
        gatherln_kernel<<<(M + 3) / 4, 256, 0, stream>>>(
            A, cursor, csr_src, invin, bs + (size_t)l * RANK,
            gammas + (size_t)l * RANK, betas + (size_t)l * RANK, B, M);
        fin = B;
        float* t = A; A = B; B = t;  // A<->B; fin points at last gatherln output
    }

    gather_kernel<<<nG, RANK, 0, stream>>>(fin, bnn, out, nG);
}

// Round 3
// 344.532 us; speedup vs baseline: 3.2726x; 1.1992x over previous
//
#include <hip/hip_runtime.h>

#define RANK 128
#define LN_EPS 1e-5f

using short8 = __attribute__((ext_vector_type(8))) short;
using v4f    = __attribute__((ext_vector_type(4))) float;

__device__ inline unsigned short f2bf(float f) {
    unsigned u = __float_as_uint(f);
    unsigned r = (u + 0x7FFF + ((u >> 16) & 1)) >> 16;   // RNE
    return (unsigned short)r;
}
__device__ inline float bf2f(unsigned short h) {
    return __uint_as_float(((unsigned)h) << 16);
}

// ---------------- histogram: in-degree (counts) + out-degree ----------------
__global__ void hist_kernel(const int* __restrict__ src, const int* __restrict__ dst,
                            int* __restrict__ counts, int* __restrict__ outdeg, int nE) {
    int e = blockIdx.x * blockDim.x + threadIdx.x;
    if (e < nE) {
        atomicAdd(&counts[dst[e]], 1);
        atomicAdd(&outdeg[src[e]], 1);
    }
}

__global__ void inv_kernel(const int* __restrict__ outdeg, const int* __restrict__ counts,
                           float* __restrict__ invout, float* __restrict__ invin, int n) {
    int i = blockIdx.x * blockDim.x + threadIdx.x;
    if (i < n) {
        invout[i] = rsqrtf(fmaxf((float)outdeg[i], 1.0f));
        invin[i]  = rsqrtf(fmaxf((float)counts[i], 1.0f));
    }
}

// ---------------- prefix scan (3-phase) ----------------
__global__ __launch_bounds__(256) void scan1_kernel(const int* __restrict__ counts,
                                                    int* __restrict__ cursor,
                                                    int* __restrict__ bsums, int n) {
    __shared__ int tmp[256];
    int tid = threadIdx.x;
    int gid = blockIdx.x * 256 + tid;
    int v = (gid < n) ? counts[gid] : 0;
    tmp[tid] = v;
    __syncthreads();
    for (int off = 1; off < 256; off <<= 1) {
        int t = (tid >= off) ? tmp[tid - off] : 0;
        __syncthreads();
        tmp[tid] += t;
        __syncthreads();
    }
    if (gid < n) cursor[gid] = tmp[tid];
    if (tid == 255) bsums[blockIdx.x] = tmp[255];
}

__global__ __launch_bounds__(256) void scan2_kernel(int* __restrict__ bsums, int nb) {
    __shared__ int tmp[256];
    int tid = threadIdx.x;
    int v = (tid < nb) ? bsums[tid] : 0;
    tmp[tid] = v;
    __syncthreads();
    for (int off = 1; off < 256; off <<= 1) {
        int t = (tid >= off) ? tmp[tid - off] : 0;
        __syncthreads();
        tmp[tid] += t;
        __syncthreads();
    }
    if (tid < nb) bsums[tid] = tmp[tid] - v;   // exclusive
}

__global__ __launch_bounds__(256) void scan3_kernel(const int* __restrict__ counts,
                                                    int* __restrict__ cursor,
                                                    const int* __restrict__ bsums, int n) {
    int gid = blockIdx.x * 256 + threadIdx.x;
    if (gid < n) cursor[gid] += bsums[blockIdx.x] - counts[gid];   // exclusive start
}

// ---------------- CSR fill (cursor becomes inclusive-end) --------
__global__ void fill_kernel(const int* __restrict__ src, const int* __restrict__ dst,
                            int* __restrict__ cursor, int* __restrict__ csr_src, int nE) {
    int e = blockIdx.x * blockDim.x + threadIdx.x;
    if (e < nE) {
        int pos = atomicAdd(&cursor[dst[e]], 1);
        csr_src[pos] = src[e];
    }
}

// ---------------- features fp32 -> bf16 ----------------
__global__ void convert_kernel(const float* __restrict__ X, unsigned* __restrict__ Xb, int n2) {
    int i = blockIdx.x * blockDim.x + threadIdx.x;   // n2 = M*64 (pairs)
    if (i < n2) {
        float2 v = ((const float2*)X)[i];
        Xb[i] = (unsigned)f2bf(v.x) | ((unsigned)f2bf(v.y) << 16);
    }
}

// ---------------- W repack to MFMA B-fragment order, fp32 -> bf16 ----------------
// Wt[l][k0][ct][lane][j] = W_l[k0*32 + (lane>>4)*8 + j][ct*16 + (lane&15)]
__global__ void repack_kernel(const float* __restrict__ Ws, short* __restrict__ Wt) {
    int l = blockIdx.x >> 3;                          // 3 layers x 8 blocks
    int s = (blockIdx.x & 7) * 256 + threadIdx.x;     // 0..2047
    int lane = s & 63, ct = (s >> 6) & 7, k0 = s >> 9;
    int m = lane & 15, quad = lane >> 4;
    const float* W = Ws + (size_t)l * RANK * RANK;
    short* o = Wt + (size_t)l * 16384 + (size_t)s * 8;
#pragma unroll
    for (int j = 0; j < 8; j++)
        o[j] = (short)f2bf(W[(k0 * 32 + quad * 8 + j) * RANK + ct * 16 + m]);
}

// ---------------- bf16 MFMA GEMM: H = (X @ W) * invout[row] ----------------
// one wave per 16 rows x 128 cols; 4 waves/block -> 64 rows/block
__global__ __launch_bounds__(256) void gemm_mfma(const short* __restrict__ Xb,
                                                 const short* __restrict__ Wt,
                                                 const float* __restrict__ invout,
                                                 unsigned short* __restrict__ H, int M) {
    int wave = threadIdx.x >> 6, lane = threadIdx.x & 63;
    int rowBase = blockIdx.x * 64 + wave * 16;
    int m = lane & 15, quad = lane >> 4;

    const short* arow = Xb + (size_t)(rowBase + m) * RANK + quad * 8;

    v4f acc[8];
#pragma unroll
    for (int ct = 0; ct < 8; ct++) acc[ct] = (v4f){0.f, 0.f, 0.f, 0.f};

#pragma unroll
    for (int k0 = 0; k0 < 4; k0++) {
        short8 a = *(const short8*)(arow + k0 * 32);
#pragma unroll
        for (int ct = 0; ct < 8; ct++) {
            short8 b = *(const short8*)(Wt + (size_t)((k0 * 8 + ct) * 64 + lane) * 8);
            acc[ct] = __builtin_amdgcn_mfma_f32_16x16x32_bf16(a, b, acc[ct], 0, 0, 0);
        }
    }

    // D layout: col = ct*16 + (lane&15), row = rowBase + quad*4 + reg
    float s[4];
    int rows[4];
#pragma unroll
    for (int r = 0; r < 4; r++) {
        rows[r] = rowBase + quad * 4 + r;
        s[r] = (rows[r] < M) ? invout[rows[r]] : 0.f;
    }
#pragma unroll
    for (int ct = 0; ct < 8; ct++) {
        int col = ct * 16 + m;
#pragma unroll
        for (int r = 0; r < 4; r++) {
            if (rows[r] < M)
                H[(size_t)rows[r] * RANK + col] = f2bf(acc[ct][r] * s[r]);
        }
    }
}

// ---------------- fused CSR gather + scale + bias + LN + ReLU (bf16 io) ----------------
__global__ __launch_bounds__(256) void gatherln_kernel(const unsigned* __restrict__ H,   // bf16x2
                                                       const int* __restrict__ cursor,   // inclusive ends
                                                       const int* __restrict__ csr_src,
                                                       const float* __restrict__ invin,
                                                       const float* __restrict__ bias,
                                                       const float* __restrict__ gamma,
                                                       const float* __restrict__ beta,
                                                       unsigned* __restrict__ out, int M) {
    int wid = threadIdx.x >> 6;
    int lane = threadIdx.x & 63;
    int node = blockIdx.x * 4 + wid;
    if (node >= M) return;

    int end = cursor[node];
    int beg = (node == 0) ? 0 : cursor[node - 1];

    float ax = 0.f, ay = 0.f;
    int e = beg;
    for (; e + 4 <= end; e += 4) {
        int s0 = csr_src[e + 0], s1 = csr_src[e + 1];
        int s2 = csr_src[e + 2], s3 = csr_src[e + 3];
        unsigned u0 = H[(size_t)s0 * 64 + lane];
        unsigned u1 = H[(size_t)s1 * 64 + lane];
        unsigned u2 = H[(size_t)s2 * 64 + lane];
        unsigned u3 = H[(size_t)s3 * 64 + lane];
        ax += __uint_as_float(u0 << 16) + __uint_as_float(u1 << 16)
            + __uint_as_float(u2 << 16) + __uint_as_float(u3 << 16);
        ay += __uint_as_float(u0 & 0xFFFF0000u) + __uint_as_float(u1 & 0xFFFF0000u)
            + __uint_as_float(u2 & 0xFFFF0000u) + __uint_as_float(u3 & 0xFFFF0000u);
    }
    for (; e < end; e++) {
        unsigned u = H[(size_t)csr_src[e] * 64 + lane];
        ax += __uint_as_float(u << 16);
        ay += __uint_as_float(u & 0xFFFF0000u);
    }

    float s = invin[node];
    float2 b = ((const float2*)bias)[lane];
    float x0 = ax * s + b.x;
    float x1 = ay * s + b.y;

    float sum = x0 + x1;
    float sq = x0 * x0 + x1 * x1;
#pragma unroll
    for (int off = 32; off > 0; off >>= 1) {
        sum += __shfl_down(sum, off);
        sq  += __shfl_down(sq, off);
    }
    sum = __shfl(sum, 0);
    sq  = __shfl(sq, 0);
    float mu = sum * (1.0f / RANK);
    float var = sq * (1.0f / RANK) - mu * mu;
    float r = rsqrtf(var + LN_EPS);

    float2 g = ((const float2*)gamma)[lane];
    float2 be = ((const float2*)beta)[lane];
    float y0 = fmaxf((x0 - mu) * r * g.x + be.x, 0.f);
    float y1 = fmaxf((x1 - mu) * r * g.y + be.y, 0.f);
    out[(size_t)node * 64 + lane] = (unsigned)f2bf(y0) | ((unsigned)f2bf(y1) << 16);
}

// ---------------- final gather: bf16 feats -> fp32 out ----------------
__global__ void gather_kernel(const unsigned short* __restrict__ feats,
                              const int* __restrict__ bnn,
                              float* __restrict__ out, int nG) {
    int g = blockIdx.x;
    int c = threadIdx.x;
    int idx = 0;
    for (int i = 0; i < g; i++) idx += bnn[i];
    out[(size_t)g * RANK + c] = bf2f(feats[(size_t)idx * RANK + c]);
}

extern "C" void kernel_launch(void* const* d_in, const int* in_sizes, int n_in,
                              void* d_out, int out_size, void* d_ws, size_t ws_size,
                              hipStream_t stream) {
    const float* features = (const float*)d_in[0];
    const int* src = (const int*)d_in[1];
    const int* dst = (const int*)d_in[2];
    const int* bnn = (const int*)d_in[3];
    const float* Ws = (const float*)d_in[4];
    const float* bs = (const float*)d_in[5];
    const float* gammas = (const float*)d_in[6];
    const float* betas = (const float*)d_in[7];
    float* out = (float*)d_out;

    int M  = in_sizes[0] / RANK;   // 50000
    int nE = in_sizes[1];          // 640000
    int nG = in_sizes[3];          // 50
    int M_pad = (M + 63) & ~63;

    char* ws = (char*)d_ws;
    size_t off = 0;
    auto alloc = [&](size_t bytes) {
        void* p = ws + off;
        off += (bytes + 255) & ~(size_t)255;
        return p;
    };
    int*   counts  = (int*)alloc((size_t)M * 4);
    int*   outdeg  = (int*)alloc((size_t)M * 4);
    int*   cursor  = (int*)alloc((size_t)M * 4);
    int*   bsums   = (int*)alloc(256 * 4);
    float* invout  = (float*)alloc((size_t)M * 4);
    float* invin   = (float*)alloc((size_t)M * 4);
    int*   csr_src = (int*)alloc((size_t)nE * 4);
    short* Wt      = (short*)alloc((size_t)3 * 16384 * 2);
    short* B0      = (short*)alloc((size_t)M_pad * RANK * 2);
    short* B1      = (short*)alloc((size_t)M_pad * RANK * 2);

    int nb = (M + 255) / 256;

    // ---- CSR build + degree normalizers ----
    hipMemsetAsync(counts, 0, (size_t)M * 4, stream);
    hipMemsetAsync(outdeg, 0, (size_t)M * 4, stream);
    hist_kernel<<<(nE + 255) / 256, 256, 0, stream>>>(src, dst, counts, outdeg, nE);
    inv_kernel<<<(M + 255) / 256, 256, 0, stream>>>(outdeg, counts, invout, invin, M);
    scan1_kernel<<<nb, 256, 0, stream>>>(counts, cursor, bsums, M);
    scan2_kernel<<<1, 256, 0, stream>>>(bsums, nb);
    scan3_kernel<<<nb, 256, 0, stream>>>(counts, cursor, bsums, M);
    fill_kernel<<<(nE + 255) / 256, 256, 0, stream>>>(src, dst, cursor, csr_src, nE);

    // ---- weight repack + feature conversion ----
    repack_kernel<<<24, 256, 0, stream>>>(Ws, Wt);
    convert_kernel<<<(M * 64 + 255) / 256, 256, 0, stream>>>(features, (unsigned*)B0, M * 64);

    // ---- 3 layers: B0 -> (gemm) -> B1 -> (gatherln) -> B0 ----
    for (int l = 0; l < 3; l++) {
        gemm_mfma<<<(M + 63) / 64, 256, 0, stream>>>(
            B0, Wt + (size_t)l * 16384, invout, (unsigned short*)B1, M);
        gatherln_kernel<<<(M + 3) / 4, 256, 0, stream>>>(
            (const unsigned*)B1, cursor, csr_src, invin, bs + (size_t)l * RANK,
            gammas + (size_t)l * RANK, betas + (size_t)l * RANK, (unsigned*)B0, M);
    }

    gather_kernel<<<nG, RANK, 0, stream>>>((const unsigned short*)B0, bnn, out, nG);
}

// Round 4
// 315.167 us; speedup vs baseline: 3.5775x; 1.0932x over previous
//
#include <hip/hip_runtime.h>

#define RANK 128
#define LN_EPS 1e-5f

// CSR-build geometry (tuned for M=50000, nE=640000)
#define NCH 4
#define CHUNK 12800            // NCH*CHUNK = 51200 >= M ; LDS = 50 KB
#define BINS (NCH * CHUNK)
#define ECH 32                 // edge chunks

using short8 = __attribute__((ext_vector_type(8))) short;
using v4f    = __attribute__((ext_vector_type(4))) float;

__device__ inline unsigned short f2bf(float f) {
    unsigned u = __float_as_uint(f);
    unsigned r = (u + 0x7FFF + ((u >> 16) & 1)) >> 16;   // RNE
    return (unsigned short)r;
}
__device__ inline float bf2f(unsigned short h) {
    return __uint_as_float(((unsigned)h) << 16);
}

// ---------------- partial histograms (no global atomics) ----------------
__global__ __launch_bounds__(256) void hist_part(const int* __restrict__ src,
                                                 const int* __restrict__ dst,
                                                 int* __restrict__ pdst,
                                                 int* __restrict__ psrc, int nE) {
    __shared__ int h[CHUNK];
    int c = blockIdx.x, n = blockIdx.y, z = blockIdx.z;
    const int* arr = z ? src : dst;
    int* pout = z ? psrc : pdst;
    int base = n * CHUNK;
    for (int i = threadIdx.x; i < CHUNK; i += 256) h[i] = 0;
    __syncthreads();
    int epc = (nE + ECH - 1) / ECH;
    int e0 = c * epc, e1 = min(e0 + epc, nE);
    for (int e = e0 + (int)threadIdx.x; e < e1; e += 256) {
        int v = arr[e] - base;
        if ((unsigned)v < (unsigned)CHUNK) atomicAdd(&h[v], 1);
    }
    __syncthreads();
    int* o = pout + (size_t)c * BINS + base;
    for (int i = threadIdx.x; i < CHUNK; i += 256) o[i] = h[i];
}

// ---------------- reduce partials -> counts + rsqrt normalizers ----------------
__global__ void reduce_part(const int* __restrict__ pdst, const int* __restrict__ psrc,
                            int* __restrict__ counts, float* __restrict__ invin,
                            float* __restrict__ invout, int M) {
    int b = blockIdx.x * blockDim.x + threadIdx.x;
    if (b >= M) return;
    int cd = 0, cs = 0;
#pragma unroll 4
    for (int c = 0; c < ECH; c++) {
        cd += pdst[(size_t)c * BINS + b];
        cs += psrc[(size_t)c * BINS + b];
    }
    counts[b] = cd;
    invin[b]  = rsqrtf(fmaxf((float)cd, 1.0f));
    invout[b] = rsqrtf(fmaxf((float)cs, 1.0f));
}

// ---------------- prefix scan (3-phase) -> inclusive ends ----------------
__global__ __launch_bounds__(256) void scan1_kernel(const int* __restrict__ counts,
                                                    int* __restrict__ ends,
                                                    int* __restrict__ bsums, int n) {
    __shared__ int tmp[256];
    int tid = threadIdx.x;
    int gid = blockIdx.x * 256 + tid;
    int v = (gid < n) ? counts[gid] : 0;
    tmp[tid] = v;
    __syncthreads();
    for (int off = 1; off < 256; off <<= 1) {
        int t = (tid >= off) ? tmp[tid - off] : 0;
        __syncthreads();
        tmp[tid] += t;
        __syncthreads();
    }
    if (gid < n) ends[gid] = tmp[tid];
    if (tid == 255) bsums[blockIdx.x] = tmp[255];
}

__global__ __launch_bounds__(256) void scan2_kernel(int* __restrict__ bsums, int nb) {
    __shared__ int tmp[256];
    int tid = threadIdx.x;
    int v = (tid < nb) ? bsums[tid] : 0;
    tmp[tid] = v;
    __syncthreads();
    for (int off = 1; off < 256; off <<= 1) {
        int t = (tid >= off) ? tmp[tid - off] : 0;
        __syncthreads();
        tmp[tid] += t;
        __syncthreads();
    }
    if (tid < nb) bsums[tid] = tmp[tid] - v;   // exclusive
}

__global__ __launch_bounds__(256) void scan3_kernel(int* __restrict__ ends,
                                                    const int* __restrict__ bsums, int n) {
    int gid = blockIdx.x * 256 + threadIdx.x;
    if (gid < n) ends[gid] += bsums[blockIdx.x];   // inclusive global ends
}

// ---------------- per-(chunk,bin) start offsets, in-place on pdst ----------------
__global__ void offs_kernel(int* __restrict__ pdst, const int* __restrict__ ends,
                            const int* __restrict__ counts, int M) {
    int b = blockIdx.x * blockDim.x + threadIdx.x;
    if (b >= M) return;
    int run = ends[b] - counts[b];
#pragma unroll 4
    for (int c = 0; c < ECH; c++) {
        size_t idx = (size_t)c * BINS + b;
        int t = pdst[idx];
        pdst[idx] = run;
        run += t;
    }
}

// ---------------- CSR fill via LDS cursors (no global atomics) ----------------
__global__ __launch_bounds__(256) void fill_sorted(const int* __restrict__ src,
                                                   const int* __restrict__ dst,
                                                   const int* __restrict__ pdst,
                                                   int* __restrict__ csr_src, int nE) {
    __shared__ int cur[CHUNK];
    int c = blockIdx.x, n = blockIdx.y;
    int base = n * CHUNK;
    const int* o = pdst + (size_t)c * BINS + base;
    for (int i = threadIdx.x; i < CHUNK; i += 256) cur[i] = o[i];
    __syncthreads();
    int epc = (nE + ECH - 1) / ECH;
    int e0 = c * epc, e1 = min(e0 + epc, nE);
    for (int e = e0 + (int)threadIdx.x; e < e1; e += 256) {
        int d = dst[e] - base;
        if ((unsigned)d < (unsigned)CHUNK) {
            int pos = atomicAdd(&cur[d], 1);   // LDS atomic
            csr_src[pos] = src[e];
        }
    }
}

// ---------------- features fp32 -> bf16 ----------------
__global__ void convert_kernel(const float* __restrict__ X, unsigned* __restrict__ Xb, int n2) {
    int i = blockIdx.x * blockDim.x + threadIdx.x;
    if (i < n2) {
        float2 v = ((const float2*)X)[i];
        Xb[i] = (unsigned)f2bf(v.x) | ((unsigned)f2bf(v.y) << 16);
    }
}

// ---------------- W repack to MFMA B-fragment order ----------------
__global__ void repack_kernel(const float* __restrict__ Ws, short* __restrict__ Wt) {
    int l = blockIdx.x >> 3;
    int s = (blockIdx.x & 7) * 256 + threadIdx.x;
    int lane = s & 63, ct = (s >> 6) & 7, k0 = s >> 9;
    int m = lane & 15, quad = lane >> 4;
    const float* W = Ws + (size_t)l * RANK * RANK;
    short* o = Wt + (size_t)l * 16384 + (size_t)s * 8;
#pragma unroll
    for (int j = 0; j < 8; j++)
        o[j] = (short)f2bf(W[(k0 * 32 + quad * 8 + j) * RANK + ct * 16 + m]);
}

// ---------------- bf16 MFMA GEMM: H = (X @ W) * invout[row] ----------------
__global__ __launch_bounds__(256) void gemm_mfma(const short* __restrict__ Xb,
                                                 const short* __restrict__ Wt,
                                                 const float* __restrict__ invout,
                                                 unsigned short* __restrict__ H, int M) {
    int wave = threadIdx.x >> 6, lane = threadIdx.x & 63;
    int rowBase = blockIdx.x * 64 + wave * 16;
    int m = lane & 15, quad = lane >> 4;

    const short* arow = Xb + (size_t)(rowBase + m) * RANK + quad * 8;

    v4f acc[8];
#pragma unroll
    for (int ct = 0; ct < 8; ct++) acc[ct] = (v4f){0.f, 0.f, 0.f, 0.f};

#pragma unroll
    for (int k0 = 0; k0 < 4; k0++) {
        short8 a = *(const short8*)(arow + k0 * 32);
#pragma unroll
        for (int ct = 0; ct < 8; ct++) {
            short8 b = *(const short8*)(Wt + (size_t)((k0 * 8 + ct) * 64 + lane) * 8);
            acc[ct] = __builtin_amdgcn_mfma_f32_16x16x32_bf16(a, b, acc[ct], 0, 0, 0);
        }
    }

    float s[4];
    int rows[4];
#pragma unroll
    for (int r = 0; r < 4; r++) {
        rows[r] = rowBase + quad * 4 + r;
        s[r] = (rows[r] < M) ? invout[rows[r]] : 0.f;
    }
#pragma unroll
    for (int ct = 0; ct < 8; ct++) {
        int col = ct * 16 + m;
#pragma unroll
        for (int r = 0; r < 4; r++) {
            if (rows[r] < M)
                H[(size_t)rows[r] * RANK + col] = f2bf(acc[ct][r] * s[r]);
        }
    }
}

// ---------------- fused CSR gather + scale + bias + LN + ReLU (bf16 io) ----------------
__global__ __launch_bounds__(256) void gatherln_kernel(const unsigned* __restrict__ H,
                                                       const int* __restrict__ ends,
                                                       const int* __restrict__ csr_src,
                                                       const float* __restrict__ invin,
                                                       const float* __restrict__ bias,
                                                       const float* __restrict__ gamma,
                                                       const float* __restrict__ beta,
                                                       unsigned* __restrict__ out, int M) {
    int wid = threadIdx.x >> 6;
    int lane = threadIdx.x & 63;
    int node = blockIdx.x * 4 + wid;
    if (node >= M) return;

    int end = ends[node];
    int beg = (node == 0) ? 0 : ends[node - 1];
    int deg = end - beg;

    // lane-parallel index fetch + shuffle broadcast (covers deg <= 64)
    int myi = 0;
    if (lane < deg) myi = csr_src[beg + lane];
    int n64 = min(deg, 64);

    float ax = 0.f, ay = 0.f;
    int j = 0;
    for (; j + 4 <= n64; j += 4) {
        int s0 = __shfl(myi, j + 0), s1 = __shfl(myi, j + 1);
        int s2 = __shfl(myi, j + 2), s3 = __shfl(myi, j + 3);
        unsigned u0 = H[(size_t)s0 * 64 + lane];
        unsigned u1 = H[(size_t)s1 * 64 + lane];
        unsigned u2 = H[(size_t)s2 * 64 + lane];
        unsigned u3 = H[(size_t)s3 * 64 + lane];
        ax += __uint_as_float(u0 << 16) + __uint_as_float(u1 << 16)
            + __uint_as_float(u2 << 16) + __uint_as_float(u3 << 16);
        ay += __uint_as_float(u0 & 0xFFFF0000u) + __uint_as_float(u1 & 0xFFFF0000u)
            + __uint_as_float(u2 & 0xFFFF0000u) + __uint_as_float(u3 & 0xFFFF0000u);
    }
    for (; j < n64; j++) {
        int s = __shfl(myi, j);
        unsigned u = H[(size_t)s * 64 + lane];
        ax += __uint_as_float(u << 16);
        ay += __uint_as_float(u & 0xFFFF0000u);
    }
    for (int e = beg + 64; e < end; e++) {     // rare tail (deg > 64)
        int s = csr_src[e];
        unsigned u = H[(size_t)s * 64 + lane];
        ax += __uint_as_float(u << 16);
        ay += __uint_as_float(u & 0xFFFF0000u);
    }

    float s = invin[node];
    float2 b = ((const float2*)bias)[lane];
    float x0 = ax * s + b.x;
    float x1 = ay * s + b.y;

    float sum = x0 + x1;
    float sq = x0 * x0 + x1 * x1;
#pragma unroll
    for (int off = 32; off > 0; off >>= 1) {
        sum += __shfl_down(sum, off);
        sq  += __shfl_down(sq, off);
    }
    sum = __shfl(sum, 0);
    sq  = __shfl(sq, 0);
    float mu = sum * (1.0f / RANK);
    float var = sq * (1.0f / RANK) - mu * mu;
    float r = rsqrtf(var + LN_EPS);

    float2 g = ((const float2*)gamma)[lane];
    float2 be = ((const float2*)beta)[lane];
    float y0 = fmaxf((x0 - mu) * r * g.x + be.x, 0.f);
    float y1 = fmaxf((x1 - mu) * r * g.y + be.y, 0.f);
    out[(size_t)node * 64 + lane] = (unsigned)f2bf(y0) | ((unsigned)f2bf(y1) << 16);
}

// ---------------- final gather: bf16 feats -> fp32 out ----------------
__global__ void gather_kernel(const unsigned short* __restrict__ feats,
                              const int* __restrict__ bnn,
                              float* __restrict__ out, int nG) {
    int g = blockIdx.x;
    int c = threadIdx.x;
    int idx = 0;
    for (int i = 0; i < g; i++) idx += bnn[i];
    out[(size_t)g * RANK + c] = bf2f(feats[(size_t)idx * RANK + c]);
}

extern "C" void kernel_launch(void* const* d_in, const int* in_sizes, int n_in,
                              void* d_out, int out_size, void* d_ws, size_t ws_size,
                              hipStream_t stream) {
    const float* features = (const float*)d_in[0];
    const int* src = (const int*)d_in[1];
    const int* dst = (const int*)d_in[2];
    const int* bnn = (const int*)d_in[3];
    const float* Ws = (const float*)d_in[4];
    const float* bs = (const float*)d_in[5];
    const float* gammas = (const float*)d_in[6];
    const float* betas = (const float*)d_in[7];
    float* out = (float*)d_out;

    int M  = in_sizes[0] / RANK;   // 50000
    int nE = in_sizes[1];          // 640000
    int nG = in_sizes[3];          // 50
    int M_pad = (M + 63) & ~63;

    char* ws = (char*)d_ws;
    size_t off = 0;
    auto alloc = [&](size_t bytes) {
        void* p = ws + off;
        off += (bytes + 255) & ~(size_t)255;
        return p;
    };
    int*   counts  = (int*)alloc((size_t)M * 4);
    int*   ends    = (int*)alloc((size_t)M * 4);
    int*   bsums   = (int*)alloc(256 * 4);
    float* invout  = (float*)alloc((size_t)M * 4);
    float* invin   = (float*)alloc((size_t)M * 4);
    int*   csr_src = (int*)alloc((size_t)nE * 4);
    short* Wt      = (short*)alloc((size_t)3 * 16384 * 2);
    short* B0      = (short*)alloc((size_t)M_pad * RANK * 2);
    short* B1      = (short*)alloc((size_t)M_pad * RANK * 2);
    int*   pdst    = (int*)alloc((size_t)ECH * BINS * 4);   // 6.55 MB
    int*   psrc    = (int*)alloc((size_t)ECH * BINS * 4);   // 6.55 MB

    int nb = (M + 255) / 256;

    // ---- atomic-free CSR build ----
    hist_part<<<dim3(ECH, NCH, 2), 256, 0, stream>>>(src, dst, pdst, psrc, nE);
    reduce_part<<<(M + 255) / 256, 256, 0, stream>>>(pdst, psrc, counts, invin, invout, M);
    scan1_kernel<<<nb, 256, 0, stream>>>(counts, ends, bsums, M);
    scan2_kernel<<<1, 256, 0, stream>>>(bsums, nb);
    scan3_kernel<<<nb, 256, 0, stream>>>(ends, bsums, M);
    offs_kernel<<<(M + 255) / 256, 256, 0, stream>>>(pdst, ends, counts, M);
    fill_sorted<<<dim3(ECH, NCH), 256, 0, stream>>>(src, dst, pdst, csr_src, nE);

    // ---- weight repack + feature conversion ----
    repack_kernel<<<24, 256, 0, stream>>>(Ws, Wt);
    convert_kernel<<<(M * 64 + 255) / 256, 256, 0, stream>>>(features, (unsigned*)B0, M * 64);

    // ---- 3 layers: B0 -> (gemm) -> B1 -> (gatherln) -> B0 ----
    for (int l = 0; l < 3; l++) {
        gemm_mfma<<<(M + 63) / 64, 256, 0, stream>>>(
            B0, Wt + (size_t)l * 16384, invout, (unsigned short*)B1, M);
        gatherln_kernel<<<(M + 3) / 4, 256, 0, stream>>>(
            (const unsigned*)B1, ends, csr_src, invin, bs + (size_t)l * RANK,
            gammas + (size_t)l * RANK, betas + (size_t)l * RANK, (unsigned*)B0, M);
    }

    gather_kernel<<<nG, RANK, 0, stream>>>((const unsigned short*)B0, bnn, out, nG);
}

// Round 5
// 267.158 us; speedup vs baseline: 4.2204x; 1.1797x over previous
//
#include <hip/hip_runtime.h>

#define RANK 128
#define LN_EPS 1e-5f

// CSR-build geometry (tuned for M=50000, nE=640000)
#define NCH 4
#define CHUNK 12800            // NCH*CHUNK = 51200 >= M ; LDS = 50 KB
#define BINS (NCH * CHUNK)
#define ECH 64                 // edge chunks
#define BT 1024                // threads per CSR-build block

using short8 = __attribute__((ext_vector_type(8))) short;
using v4f    = __attribute__((ext_vector_type(4))) float;

__device__ inline unsigned short f2bf(float f) {
    unsigned u = __float_as_uint(f);
    unsigned r = (u + 0x7FFF + ((u >> 16) & 1)) >> 16;   // RNE
    return (unsigned short)r;
}
__device__ inline float bf2f(unsigned short h) {
    return __uint_as_float(((unsigned)h) << 16);
}

// ---------------- partial histograms (no global atomics) ----------------
__global__ __launch_bounds__(BT) void hist_part(const int* __restrict__ src,
                                                const int* __restrict__ dst,
                                                int* __restrict__ pdst,
                                                int* __restrict__ psrc, int nE) {
    __shared__ int h[CHUNK];
    int c = blockIdx.x, n = blockIdx.y, z = blockIdx.z;
    const int* arr = z ? src : dst;
    int* pout = z ? psrc : pdst;
    int base = n * CHUNK;
    for (int i = threadIdx.x; i < CHUNK; i += BT) h[i] = 0;
    __syncthreads();
    int epc = (nE + ECH - 1) / ECH;
    int e0 = c * epc, e1 = min(e0 + epc, nE);
    for (int e = e0 + (int)threadIdx.x; e < e1; e += BT) {
        int v = arr[e] - base;
        if ((unsigned)v < (unsigned)CHUNK) atomicAdd(&h[v], 1);
    }
    __syncthreads();
    int* o = pout + (size_t)c * BINS + base;
    for (int i = threadIdx.x; i < CHUNK; i += BT) o[i] = h[i];
}

// ---------------- reduce partials -> counts + rsqrt normalizers ----------------
__global__ void reduce_part(const int* __restrict__ pdst, const int* __restrict__ psrc,
                            int* __restrict__ counts, float* __restrict__ invin,
                            float* __restrict__ invout, int M) {
    int b = blockIdx.x * blockDim.x + threadIdx.x;
    if (b >= M) return;
    int cd = 0, cs = 0;
#pragma unroll 8
    for (int c = 0; c < ECH; c++) {
        cd += pdst[(size_t)c * BINS + b];
        cs += psrc[(size_t)c * BINS + b];
    }
    counts[b] = cd;
    invin[b]  = rsqrtf(fmaxf((float)cd, 1.0f));
    invout[b] = rsqrtf(fmaxf((float)cs, 1.0f));
}

// ---------------- prefix scan (3-phase) -> inclusive ends ----------------
__global__ __launch_bounds__(256) void scan1_kernel(const int* __restrict__ counts,
                                                    int* __restrict__ ends,
                                                    int* __restrict__ bsums, int n) {
    __shared__ int tmp[256];
    int tid = threadIdx.x;
    int gid = blockIdx.x * 256 + tid;
    int v = (gid < n) ? counts[gid] : 0;
    tmp[tid] = v;
    __syncthreads();
    for (int off = 1; off < 256; off <<= 1) {
        int t = (tid >= off) ? tmp[tid - off] : 0;
        __syncthreads();
        tmp[tid] += t;
        __syncthreads();
    }
    if (gid < n) ends[gid] = tmp[tid];
    if (tid == 255) bsums[blockIdx.x] = tmp[255];
}

__global__ __launch_bounds__(256) void scan2_kernel(int* __restrict__ bsums, int nb) {
    __shared__ int tmp[256];
    int tid = threadIdx.x;
    int v = (tid < nb) ? bsums[tid] : 0;
    tmp[tid] = v;
    __syncthreads();
    for (int off = 1; off < 256; off <<= 1) {
        int t = (tid >= off) ? tmp[tid - off] : 0;
        __syncthreads();
        tmp[tid] += t;
        __syncthreads();
    }
    if (tid < nb) bsums[tid] = tmp[tid] - v;   // exclusive
}

__global__ __launch_bounds__(256) void scan3_kernel(int* __restrict__ ends,
                                                    const int* __restrict__ bsums, int n) {
    int gid = blockIdx.x * 256 + threadIdx.x;
    if (gid < n) ends[gid] += bsums[blockIdx.x];   // inclusive global ends
}

// ---------------- per-(chunk,bin) start offsets, in-place on pdst ----------------
__global__ void offs_kernel(int* __restrict__ pdst, const int* __restrict__ ends,
                            const int* __restrict__ counts, int M) {
    int b = blockIdx.x * blockDim.x + threadIdx.x;
    if (b >= M) return;
    int run = ends[b] - counts[b];
#pragma unroll 8
    for (int c = 0; c < ECH; c++) {
        size_t idx = (size_t)c * BINS + b;
        int t = pdst[idx];
        pdst[idx] = run;
        run += t;
    }
}

// ---------------- CSR fill via LDS cursors (no global atomics) ----------------
__global__ __launch_bounds__(BT) void fill_sorted(const int* __restrict__ src,
                                                  const int* __restrict__ dst,
                                                  const int* __restrict__ pdst,
                                                  int* __restrict__ csr_src, int nE) {
    __shared__ int cur[CHUNK];
    int c = blockIdx.x, n = blockIdx.y;
    int base = n * CHUNK;
    const int* o = pdst + (size_t)c * BINS + base;
    for (int i = threadIdx.x; i < CHUNK; i += BT) cur[i] = o[i];
    __syncthreads();
    int epc = (nE + ECH - 1) / ECH;
    int e0 = c * epc, e1 = min(e0 + epc, nE);
    for (int e = e0 + (int)threadIdx.x; e < e1; e += BT) {
        int d = dst[e] - base;
        if ((unsigned)d < (unsigned)CHUNK) {
            int pos = atomicAdd(&cur[d], 1);   // LDS atomic
            csr_src[pos] = src[e];
        }
    }
}

// ---------------- features fp32 -> bf16 ----------------
__global__ void convert_kernel(const float* __restrict__ X, unsigned* __restrict__ Xb, int n2) {
    int i = blockIdx.x * blockDim.x + threadIdx.x;
    if (i < n2) {
        float2 v = ((const float2*)X)[i];
        Xb[i] = (unsigned)f2bf(v.x) | ((unsigned)f2bf(v.y) << 16);
    }
}

// ---------------- W repack to MFMA B-fragment order ----------------
__global__ void repack_kernel(const float* __restrict__ Ws, short* __restrict__ Wt) {
    int l = blockIdx.x >> 3;
    int s = (blockIdx.x & 7) * 256 + threadIdx.x;
    int lane = s & 63, ct = (s >> 6) & 7, k0 = s >> 9;
    int m = lane & 15, quad = lane >> 4;
    const float* W = Ws + (size_t)l * RANK * RANK;
    short* o = Wt + (size_t)l * 16384 + (size_t)s * 8;
#pragma unroll
    for (int j = 0; j < 8; j++)
        o[j] = (short)f2bf(W[(k0 * 32 + quad * 8 + j) * RANK + ct * 16 + m]);
}

// ---------------- bf16 MFMA GEMM: H = (X @ W) * invout[row] ----------------
__global__ __launch_bounds__(256) void gemm_mfma(const short* __restrict__ Xb,
                                                 const short* __restrict__ Wt,
                                                 const float* __restrict__ invout,
                                                 unsigned short* __restrict__ H, int M) {
    int wave = threadIdx.x >> 6, lane = threadIdx.x & 63;
    int rowBase = blockIdx.x * 64 + wave * 16;
    int m = lane & 15, quad = lane >> 4;

    const short* arow = Xb + (size_t)(rowBase + m) * RANK + quad * 8;

    v4f acc[8];
#pragma unroll
    for (int ct = 0; ct < 8; ct++) acc[ct] = (v4f){0.f, 0.f, 0.f, 0.f};

#pragma unroll
    for (int k0 = 0; k0 < 4; k0++) {
        short8 a = *(const short8*)(arow + k0 * 32);
#pragma unroll
        for (int ct = 0; ct < 8; ct++) {
            short8 b = *(const short8*)(Wt + (size_t)((k0 * 8 + ct) * 64 + lane) * 8);
            acc[ct] = __builtin_amdgcn_mfma_f32_16x16x32_bf16(a, b, acc[ct], 0, 0, 0);
        }
    }

    float s[4];
    int rows[4];
#pragma unroll
    for (int r = 0; r < 4; r++) {
        rows[r] = rowBase + quad * 4 + r;
        s[r] = (rows[r] < M) ? invout[rows[r]] : 0.f;
    }
#pragma unroll
    for (int ct = 0; ct < 8; ct++) {
        int col = ct * 16 + m;
#pragma unroll
        for (int r = 0; r < 4; r++) {
            if (rows[r] < M)
                H[(size_t)rows[r] * RANK + col] = f2bf(acc[ct][r] * s[r]);
        }
    }
}

// ---------------- fused CSR gather + scale + bias + LN + ReLU (bf16 io) ----------------
__global__ __launch_bounds__(256) void gatherln_kernel(const unsigned* __restrict__ H,
                                                       const int* __restrict__ ends,
                                                       const int* __restrict__ csr_src,
                                                       const float* __restrict__ invin,
                                                       const float* __restrict__ bias,
                                                       const float* __restrict__ gamma,
                                                       const float* __restrict__ beta,
                                                       unsigned* __restrict__ out, int M) {
    int wid = threadIdx.x >> 6;
    int lane = threadIdx.x & 63;
    int node = blockIdx.x * 4 + wid;
    if (node >= M) return;

    int end = ends[node];
    int beg = (node == 0) ? 0 : ends[node - 1];
    int deg = end - beg;

    // lane-parallel index fetch + shuffle broadcast (covers deg <= 64)
    int myi = 0;
    if (lane < deg) myi = csr_src[beg + lane];
    int n64 = min(deg, 64);

    float ax = 0.f, ay = 0.f;
    int j = 0;
    for (; j + 4 <= n64; j += 4) {
        int s0 = __shfl(myi, j + 0), s1 = __shfl(myi, j + 1);
        int s2 = __shfl(myi, j + 2), s3 = __shfl(myi, j + 3);
        unsigned u0 = H[(size_t)s0 * 64 + lane];
        unsigned u1 = H[(size_t)s1 * 64 + lane];
        unsigned u2 = H[(size_t)s2 * 64 + lane];
        unsigned u3 = H[(size_t)s3 * 64 + lane];
        ax += __uint_as_float(u0 << 16) + __uint_as_float(u1 << 16)
            + __uint_as_float(u2 << 16) + __uint_as_float(u3 << 16);
        ay += __uint_as_float(u0 & 0xFFFF0000u) + __uint_as_float(u1 & 0xFFFF0000u)
            + __uint_as_float(u2 & 0xFFFF0000u) + __uint_as_float(u3 & 0xFFFF0000u);
    }
    for (; j < n64; j++) {
        int s = __shfl(myi, j);
        unsigned u = H[(size_t)s * 64 + lane];
        ax += __uint_as_float(u << 16);
        ay += __uint_as_float(u & 0xFFFF0000u);
    }
    for (int e = beg + 64; e < end; e++) {     // rare tail (deg > 64)
        int s = csr_src[e];
        unsigned u = H[(size_t)s * 64 + lane];
        ax += __uint_as_float(u << 16);
        ay += __uint_as_float(u & 0xFFFF0000u);
    }

    float s = invin[node];
    float2 b = ((const float2*)bias)[lane];
    float x0 = ax * s + b.x;
    float x1 = ay * s + b.y;

    float sum = x0 + x1;
    float sq = x0 * x0 + x1 * x1;
#pragma unroll
    for (int off = 32; off > 0; off >>= 1) {
        sum += __shfl_down(sum, off);
        sq  += __shfl_down(sq, off);
    }
    sum = __shfl(sum, 0);
    sq  = __shfl(sq, 0);
    float mu = sum * (1.0f / RANK);
    float var = sq * (1.0f / RANK) - mu * mu;
    float r = rsqrtf(var + LN_EPS);

    float2 g = ((const float2*)gamma)[lane];
    float2 be = ((const float2*)beta)[lane];
    float y0 = fmaxf((x0 - mu) * r * g.x + be.x, 0.f);
    float y1 = fmaxf((x1 - mu) * r * g.y + be.y, 0.f);
    out[(size_t)node * 64 + lane] = (unsigned)f2bf(y0) | ((unsigned)f2bf(y1) << 16);
}

// ---------------- final gather: bf16 feats -> fp32 out ----------------
__global__ void gather_kernel(const unsigned short* __restrict__ feats,
                              const int* __restrict__ bnn,
                              float* __restrict__ out, int nG) {
    int g = blockIdx.x;
    int c = threadIdx.x;
    int idx = 0;
    for (int i = 0; i < g; i++) idx += bnn[i];
    out[(size_t)g * RANK + c] = bf2f(feats[(size_t)idx * RANK + c]);
}

extern "C" void kernel_launch(void* const* d_in, const int* in_sizes, int n_in,
                              void* d_out, int out_size, void* d_ws, size_t ws_size,
                              hipStream_t stream) {
    const float* features = (const float*)d_in[0];
    const int* src = (const int*)d_in[1];
    const int* dst = (const int*)d_in[2];
    const int* bnn = (const int*)d_in[3];
    const float* Ws = (const float*)d_in[4];
    const float* bs = (const float*)d_in[5];
    const float* gammas = (const float*)d_in[6];
    const float* betas = (const float*)d_in[7];
    float* out = (float*)d_out;

    int M  = in_sizes[0] / RANK;   // 50000
    int nE = in_sizes[1];          // 640000
    int nG = in_sizes[3];          // 50
    int M_pad = (M + 63) & ~63;

    char* ws = (char*)d_ws;
    size_t off = 0;
    auto alloc = [&](size_t bytes) {
        void* p = ws + off;
        off += (bytes + 255) & ~(size_t)255;
        return p;
    };
    int*   counts  = (int*)alloc((size_t)M * 4);
    int*   ends    = (int*)alloc((size_t)M * 4);
    int*   bsums   = (int*)alloc(256 * 4);
    float* invout  = (float*)alloc((size_t)M * 4);
    float* invin   = (float*)alloc((size_t)M * 4);
    int*   csr_src = (int*)alloc((size_t)nE * 4);
    short* Wt      = (short*)alloc((size_t)3 * 16384 * 2);
    short* B0      = (short*)alloc((size_t)M_pad * RANK * 2);
    short* B1      = (short*)alloc((size_t)M_pad * RANK * 2);
    int*   pdst    = (int*)alloc((size_t)ECH * BINS * 4);   // 13.1 MB
    int*   psrc    = (int*)alloc((size_t)ECH * BINS * 4);   // 13.1 MB

    int nb = (M + 255) / 256;

    // ---- atomic-free CSR build ----
    hist_part<<<dim3(ECH, NCH, 2), BT, 0, stream>>>(src, dst, pdst, psrc, nE);
    reduce_part<<<(M + 255) / 256, 256, 0, stream>>>(pdst, psrc, counts, invin, invout, M);
    scan1_kernel<<<nb, 256, 0, stream>>>(counts, ends, bsums, M);
    scan2_kernel<<<1, 256, 0, stream>>>(bsums, nb);
    scan3_kernel<<<nb, 256, 0, stream>>>(ends, bsums, M);
    offs_kernel<<<(M + 255) / 256, 256, 0, stream>>>(pdst, ends, counts, M);
    fill_sorted<<<dim3(ECH, NCH), BT, 0, stream>>>(src, dst, pdst, csr_src, nE);

    // ---- weight repack + feature conversion ----
    repack_kernel<<<24, 256, 0, stream>>>(Ws, Wt);
    convert_kernel<<<(M * 64 + 255) / 256, 256, 0, stream>>>(features, (unsigned*)B0, M * 64);

    // ---- 3 layers: B0 -> (gemm) -> B1 -> (gatherln) -> B0 ----
    for (int l = 0; l < 3; l++) {
        gemm_mfma<<<(M + 63) / 64, 256, 0, stream>>>(
            B0, Wt + (size_t)l * 16384, invout, (unsigned short*)B1, M);
        gatherln_kernel<<<(M + 3) / 4, 256, 0, stream>>>(
            (const unsigned*)B1, ends, csr_src, invin, bs + (size_t)l * RANK,
            gammas + (size_t)l * RANK, betas + (size_t)l * RANK, (unsigned*)B0, M);
    }

    gather_kernel<<<nG, RANK, 0, stream>>>((const unsigned short*)B0, bnn, out, nG);
}